// Round 1
// baseline (869.137 us; speedup 1.0000x reference)
//
#include <hip/hip_runtime.h>

#define TT   2048
#define BSZ  64
#define DD0  256
#define DD1  128
#define DD2  3
#define NROW (DD1*BSZ)   // 8192 rows, r = o*64 + b

typedef __attribute__((ext_vector_type(8))) short short8;
typedef __attribute__((ext_vector_type(4))) float f32x4;

__device__ __forceinline__ unsigned short f2b(float f) {
  unsigned u = __builtin_bit_cast(unsigned, f);
  unsigned r = (u + 0x7fffu + ((u >> 16) & 1u)) >> 16;   // RNE
  return (unsigned short)r;
}
__device__ __forceinline__ float b2f(unsigned short s) {
  unsigned u = ((unsigned)s) << 16;
  return __builtin_bit_cast(float, u);
}

// ---------------------------------------------------------------- transpose+cvt
// Wt[s][t] = bf16(W[t][s]); tiles 64x64
__global__ __launch_bounds__(256) void transpose_w(
    const float* __restrict__ W, unsigned short* __restrict__ Wt)
{
  __shared__ unsigned short tile[64][65];
  const int tt = blockIdx.x * 64;   // t base (rows of W)
  const int ss = blockIdx.y * 64;   // s base (cols of W)
  const int tid = threadIdx.x;
#pragma unroll
  for (int i = 0; i < 16; ++i) {
    int e = i * 256 + tid;
    int r = e >> 6, c = e & 63;                 // r: t-off, c: s-off
    tile[c][r] = f2b(W[(tt + r) * TT + ss + c]);
  }
  __syncthreads();
#pragma unroll
  for (int i = 0; i < 16; ++i) {
    int e = i * 256 + tid;
    int r = e >> 6, c = e & 63;                 // r: s-off, c: t-off
    Wt[(size_t)(ss + r) * TT + tt + c] = tile[r][c];
  }
}

// ---------------------------------------------------------------- projection
// Dout[(o*64+b)*T + t] = bf16( sum_d W1[o][d] * X[b][d][t] )
__global__ __launch_bounds__(256) void proj_kernel(
    const float* __restrict__ X, const float* __restrict__ W1,
    unsigned short* __restrict__ Dout)
{
  __shared__ __align__(16) unsigned short Al[DD1 * 72];   // [o=128][d=64 pad 72]
  __shared__ __align__(16) unsigned short Bl[128 * 72];   // [t=128][d=64 pad 72]
  const int tid = threadIdx.x;
  const int b  = blockIdx.y;
  const int t0 = blockIdx.x * 128;
  const int w = tid >> 6, l = tid & 63;

  f32x4 acc[2][8];
#pragma unroll
  for (int m = 0; m < 2; ++m)
#pragma unroll
    for (int n = 0; n < 8; ++n) acc[m][n] = f32x4{0.f, 0.f, 0.f, 0.f};

  for (int k0 = 0; k0 < DD0; k0 += 64) {
#pragma unroll
    for (int i = 0; i < 32; ++i) {              // A: W1 128x64
      int e = i * 256 + tid;
      int o = e >> 6, d = e & 63;
      Al[o * 72 + d] = f2b(W1[o * DD0 + k0 + d]);
    }
#pragma unroll
    for (int i = 0; i < 32; ++i) {              // B: X[b] 64x128 -> [t][d]
      int e = i * 256 + tid;
      int d = e >> 7, t = e & 127;
      Bl[t * 72 + d] = f2b(X[(size_t)(b * DD0 + k0 + d) * TT + t0 + t]);
    }
    __syncthreads();
#pragma unroll
    for (int kk = 0; kk < 2; ++kk) {
      const int koff = (l >> 4) * 8 + kk * 32;
      short8 a0 = *(const short8*)&Al[(w * 32 + 0  + (l & 15)) * 72 + koff];
      short8 a1 = *(const short8*)&Al[(w * 32 + 16 + (l & 15)) * 72 + koff];
#pragma unroll
      for (int n = 0; n < 8; ++n) {
        short8 bv = *(const short8*)&Bl[(n * 16 + (l & 15)) * 72 + koff];
        acc[0][n] = __builtin_amdgcn_mfma_f32_16x16x32_bf16(a0, bv, acc[0][n], 0, 0, 0);
        acc[1][n] = __builtin_amdgcn_mfma_f32_16x16x32_bf16(a1, bv, acc[1][n], 0, 0, 0);
      }
    }
    __syncthreads();
  }
#pragma unroll
  for (int m = 0; m < 2; ++m)
#pragma unroll
    for (int n = 0; n < 8; ++n)
#pragma unroll
      for (int r = 0; r < 4; ++r) {
        int o = w * 32 + m * 16 + (l >> 4) * 4 + r;
        int t = t0 + n * 16 + (l & 15);
        Dout[(size_t)(o * BSZ + b) * TT + t] = f2b(acc[m][n][r]);
      }
}

// ---------------------------------------------------------------- DFSMN stage
// E = Din @ W (via Wt), A = softmax_b(E), Mn = Din*A + Mprev, Dout = Din + Mn
template <int FIRST>
__global__ __launch_bounds__(256) void stage_kernel(
    const unsigned short* __restrict__ Din,
    const unsigned short* __restrict__ Wt,
    unsigned short* __restrict__ M,
    unsigned short* __restrict__ Dout)
{
  __shared__ __align__(16) unsigned short Al[64 * 72];    // [b=64][k=64 pad 72]
  __shared__ __align__(16) unsigned short Bl[128 * 72];   // [s=128][k=64 pad 72]
  const int tid = threadIdx.x;
  const int o  = blockIdx.y;
  const int s0 = blockIdx.x * 128;
  const int w = tid >> 6, l = tid & 63;
  const int r0 = o * BSZ;

  f32x4 acc[4][2];
#pragma unroll
  for (int m = 0; m < 4; ++m)
#pragma unroll
    for (int n = 0; n < 2; ++n) acc[m][n] = f32x4{0.f, 0.f, 0.f, 0.f};

  for (int k0 = 0; k0 < TT; k0 += 64) {
#pragma unroll
    for (int i = 0; i < 2; ++i) {               // A: 64x64 bf16
      int e = i * 256 + tid;
      int row = e >> 3, ch = e & 7;
      short8 v = *(const short8*)&Din[(size_t)(r0 + row) * TT + k0 + ch * 8];
      *(short8*)&Al[row * 72 + ch * 8] = v;
    }
#pragma unroll
    for (int i = 0; i < 4; ++i) {               // B: 128x64 bf16 (Wt rows)
      int e = i * 256 + tid;
      int row = e >> 3, ch = e & 7;
      short8 v = *(const short8*)&Wt[(size_t)(s0 + row) * TT + k0 + ch * 8];
      *(short8*)&Bl[row * 72 + ch * 8] = v;
    }
    __syncthreads();
#pragma unroll
    for (int kk = 0; kk < 2; ++kk) {
      const int koff = (l >> 4) * 8 + kk * 32;
      short8 a[4];
#pragma unroll
      for (int m = 0; m < 4; ++m)
        a[m] = *(const short8*)&Al[(m * 16 + (l & 15)) * 72 + koff];
#pragma unroll
      for (int n = 0; n < 2; ++n) {
        short8 bv = *(const short8*)&Bl[(w * 32 + n * 16 + (l & 15)) * 72 + koff];
#pragma unroll
        for (int m = 0; m < 4; ++m)
          acc[m][n] = __builtin_amdgcn_mfma_f32_16x16x32_bf16(a[m], bv, acc[m][n], 0, 0, 0);
      }
    }
    __syncthreads();
  }

  // fused epilogue: per-column softmax over the 64 rows (= batch axis) + gating
#pragma unroll
  for (int n = 0; n < 2; ++n) {
    float mx = -3.0e38f;
#pragma unroll
    for (int m = 0; m < 4; ++m)
#pragma unroll
      for (int r = 0; r < 4; ++r) mx = fmaxf(mx, acc[m][n][r]);
    mx = fmaxf(mx, __shfl_xor(mx, 16));
    mx = fmaxf(mx, __shfl_xor(mx, 32));
    float sm = 0.0f;
#pragma unroll
    for (int m = 0; m < 4; ++m)
#pragma unroll
      for (int r = 0; r < 4; ++r) sm += __expf(acc[m][n][r] - mx);
    sm += __shfl_xor(sm, 16);
    sm += __shfl_xor(sm, 32);
    const float rs = 1.0f / sm;
    const int col = s0 + w * 32 + n * 16 + (l & 15);
#pragma unroll
    for (int m = 0; m < 4; ++m)
#pragma unroll
      for (int r = 0; r < 4; ++r) {
        int row = m * 16 + (l >> 4) * 4 + r;    // b index
        size_t idx = (size_t)(r0 + row) * TT + col;
        float a  = __expf(acc[m][n][r] - mx) * rs;
        float d  = b2f(Din[idx]);
        float mp = FIRST ? 0.0f : b2f(M[idx]);
        float mn = fmaf(d, a, mp);
        float dn = d + mn;
        M[idx]    = f2b(mn);
        Dout[idx] = f2b(dn);
      }
  }
}

// ---------------------------------------------------------------- output proj
// Y[b][o][j] = sum_t D4[(o*64+b)*T+t] * W2[t][j] + B[o][j]
__global__ __launch_bounds__(256) void out_proj(
    const unsigned short* __restrict__ D4, const float* __restrict__ W2,
    const float* __restrict__ Bb, float* __restrict__ Y)
{
  const int r = blockIdx.x;          // o*64 + b
  const int o = r >> 6, b = r & 63;
  const int tid = threadIdx.x;
  float p0 = 0.f, p1 = 0.f, p2 = 0.f;
  for (int t = tid; t < TT; t += 256) {
    float d = b2f(D4[(size_t)r * TT + t]);
    p0 = fmaf(d, W2[t * 3 + 0], p0);
    p1 = fmaf(d, W2[t * 3 + 1], p1);
    p2 = fmaf(d, W2[t * 3 + 2], p2);
  }
#pragma unroll
  for (int off = 1; off < 64; off <<= 1) {
    p0 += __shfl_xor(p0, off);
    p1 += __shfl_xor(p1, off);
    p2 += __shfl_xor(p2, off);
  }
  __shared__ float red[4][3];
  const int w = tid >> 6, l = tid & 63;
  if (l == 0) { red[w][0] = p0; red[w][1] = p1; red[w][2] = p2; }
  __syncthreads();
  if (tid < 3) {
    float s = red[0][tid] + red[1][tid] + red[2][tid] + red[3][tid];
    Y[(size_t)(b * DD1 + o) * DD2 + tid] = s + Bb[o * DD2 + tid];
  }
}

// ---------------------------------------------------------------- launch
extern "C" void kernel_launch(void* const* d_in, const int* in_sizes, int n_in,
                              void* d_out, int out_size, void* d_ws, size_t ws_size,
                              hipStream_t stream)
{
  const float* X  = (const float*)d_in[0];
  const float* W1 = (const float*)d_in[1];
  const float* DW[4] = {(const float*)d_in[2], (const float*)d_in[3],
                        (const float*)d_in[4], (const float*)d_in[5]};
  const float* W2 = (const float*)d_in[6];
  const float* Bb = (const float*)d_in[7];
  float* Y = (float*)d_out;

  unsigned short* ws = (unsigned short*)d_ws;
  unsigned short* Wt[4];
  for (int i = 0; i < 4; ++i) Wt[i] = ws + (size_t)i * TT * TT;
  unsigned short* Dbuf0 = ws + (size_t)4 * TT * TT;
  unsigned short* Dbuf1 = Dbuf0 + (size_t)NROW * TT;
  unsigned short* Mbuf  = Dbuf1 + (size_t)NROW * TT;
  // total ws use: (4*TT*TT + 3*NROW*TT)*2 = 128 MiB

  dim3 blk(256);
  for (int i = 0; i < 4; ++i)
    transpose_w<<<dim3(TT / 64, TT / 64), blk, 0, stream>>>(DW[i], Wt[i]);

  proj_kernel<<<dim3(TT / 128, BSZ), blk, 0, stream>>>(X, W1, Dbuf0);

  stage_kernel<1><<<dim3(TT / 128, DD1), blk, 0, stream>>>(Dbuf0, Wt[0], Mbuf, Dbuf1);
  stage_kernel<0><<<dim3(TT / 128, DD1), blk, 0, stream>>>(Dbuf1, Wt[1], Mbuf, Dbuf0);
  stage_kernel<0><<<dim3(TT / 128, DD1), blk, 0, stream>>>(Dbuf0, Wt[2], Mbuf, Dbuf1);
  stage_kernel<0><<<dim3(TT / 128, DD1), blk, 0, stream>>>(Dbuf1, Wt[3], Mbuf, Dbuf0);

  out_proj<<<dim3(NROW), blk, 0, stream>>>(Dbuf0, W2, Bb, Y);
}

// Round 2
// 818.320 us; speedup vs baseline: 1.0621x; 1.0621x over previous
//
#include <hip/hip_runtime.h>

#define TT   2048
#define BSZ  64
#define DD0  256
#define DD1  128
#define DD2  3
#define NROW (DD1*BSZ)   // 8192 rows, r = o*64 + b

typedef __attribute__((ext_vector_type(8))) short short8;
typedef __attribute__((ext_vector_type(4))) float f32x4;
typedef __attribute__((ext_vector_type(4))) unsigned short us4;

__device__ __forceinline__ unsigned short f2b(float f) {
  unsigned u = __builtin_bit_cast(unsigned, f);
  unsigned r = (u + 0x7fffu + ((u >> 16) & 1u)) >> 16;   // RNE
  return (unsigned short)r;
}
__device__ __forceinline__ float b2f(unsigned short s) {
  unsigned u = ((unsigned)s) << 16;
  return __builtin_bit_cast(float, u);
}

// async global->LDS, 16B per lane. lds ptr must be the WAVE-UNIFORM base;
// HW writes base + lane*16. Global src is per-lane.
__device__ __forceinline__ void gload16(const void* g, void* l) {
  __builtin_amdgcn_global_load_lds(
      (const __attribute__((address_space(1))) unsigned int*)(unsigned long long)g,
      (__attribute__((address_space(3))) unsigned int*)(unsigned int)(unsigned long long)l,
      16, 0, 0);
}

// ------------------------------------------------------- transpose + f32->bf16
// dst[(c0+c)*R + r] = bf16(src[r*C + c0+c]); 64x64 tiles, z-batched.
__global__ __launch_bounds__(256) void transpose_cvt(
    const float* __restrict__ src, unsigned short* __restrict__ dst,
    int R, int C, long sstride, long dstride)
{
  __shared__ float tile[64 * 65];
  const int z = blockIdx.z;
  src += (size_t)z * sstride;
  dst += (size_t)z * dstride;
  const int c0 = blockIdx.x * 64, r0 = blockIdx.y * 64;
  const int tid = threadIdx.x;
#pragma unroll
  for (int i = 0; i < 4; ++i) {
    int e = i * 256 + tid;
    int r = e >> 4, q = e & 15;
    float4 v = *(const float4*)&src[(size_t)(r0 + r) * C + c0 + q * 4];
    tile[r * 65 + q * 4 + 0] = v.x;
    tile[r * 65 + q * 4 + 1] = v.y;
    tile[r * 65 + q * 4 + 2] = v.z;
    tile[r * 65 + q * 4 + 3] = v.w;
  }
  __syncthreads();
#pragma unroll
  for (int i = 0; i < 4; ++i) {
    int e = i * 256 + tid;
    int c = e >> 4, q = e & 15;
    us4 o;
    o[0] = f2b(tile[(q * 4 + 0) * 65 + c]);
    o[1] = f2b(tile[(q * 4 + 1) * 65 + c]);
    o[2] = f2b(tile[(q * 4 + 2) * 65 + c]);
    o[3] = f2b(tile[(q * 4 + 3) * 65 + c]);
    *(us4*)&dst[(size_t)(c0 + c) * R + r0 + q * 4] = o;
  }
}

// ------------------------------------------------------------------ projection
// Dout[(o*64+b)*T + t] = bf16( sum_d W1[o][d] * Xt[b][t][d] )
// BM=128 (o), BN=128 (t), BK=64, K=256. A reg-staged (f32->bf16), B gload_lds.
__global__ __launch_bounds__(256) void proj_kernel(
    const float* __restrict__ W1, const unsigned short* __restrict__ Xt,
    unsigned short* __restrict__ Dout)
{
  __shared__ __align__(16) unsigned short Al[128 * 72];  // padded, reg-staged
  __shared__ __align__(16) unsigned short Bl[128 * 64];  // linear + XOR swizzle
  const int tid = threadIdx.x;
  const int b = blockIdx.y, t0 = blockIdx.x * 128;
  const int w = tid >> 6, l = tid & 63;
  const unsigned short* XtB = Xt + ((size_t)b * TT + t0) * DD0;

  f32x4 acc[8][2];
#pragma unroll
  for (int m = 0; m < 8; ++m)
#pragma unroll
    for (int n = 0; n < 2; ++n) acc[m][n] = f32x4{0.f, 0.f, 0.f, 0.f};

  for (int k0 = 0; k0 < DD0; k0 += 64) {
    // A: 128 rows x 8 units(16B); u -> row=u>>3, cg=u&7
#pragma unroll
    for (int i = 0; i < 4; ++i) {
      int u = i * 256 + tid;
      int row = u >> 3, cg = u & 7;
      const float* s = &W1[row * DD0 + k0 + cg * 8];
      float4 v0 = *(const float4*)s;
      float4 v1 = *(const float4*)(s + 4);
      short8 p;
      p[0] = f2b(v0.x); p[1] = f2b(v0.y); p[2] = f2b(v0.z); p[3] = f2b(v0.w);
      p[4] = f2b(v1.x); p[5] = f2b(v1.y); p[6] = f2b(v1.z); p[7] = f2b(v1.w);
      *(short8*)&Al[row * 72 + cg * 8] = p;
    }
    // B: 16 KB = 16 wave-chunks of 1KB; wave w gets 4
#pragma unroll
    for (int c = 0; c < 4; ++c) {
      int ob = (w * 4 + c) * 1024;
      int off = ob + l * 16;
      int row = off >> 7, c16 = (off >> 4) & 7;
      gload16((const char*)XtB + ((size_t)row * DD0 + k0) * 2 + ((c16 ^ (row & 7)) * 16),
              (char*)Bl + ob);
    }
    __syncthreads();
#pragma unroll
    for (int kk = 0; kk < 2; ++kk) {
      const int q = l >> 4;
      short8 bfr[2];
#pragma unroll
      for (int n = 0; n < 2; ++n) {
        int row = w * 32 + n * 16 + (l & 15);
        int c16 = (kk * 4 + q) ^ (row & 7);
        bfr[n] = *(const short8*)&Bl[row * 64 + c16 * 8];
      }
#pragma unroll
      for (int m = 0; m < 8; ++m) {
        int row = m * 16 + (l & 15);
        short8 a = *(const short8*)&Al[row * 72 + (kk * 4 + q) * 8];
        acc[m][0] = __builtin_amdgcn_mfma_f32_16x16x32_bf16(a, bfr[0], acc[m][0], 0, 0, 0);
        acc[m][1] = __builtin_amdgcn_mfma_f32_16x16x32_bf16(a, bfr[1], acc[m][1], 0, 0, 0);
      }
    }
    __syncthreads();
  }
#pragma unroll
  for (int m = 0; m < 8; ++m)
#pragma unroll
    for (int n = 0; n < 2; ++n)
#pragma unroll
      for (int r = 0; r < 4; ++r) {
        int o = m * 16 + (l >> 4) * 4 + r;
        int t = t0 + w * 32 + n * 16 + (l & 15);
        Dout[(size_t)(o * BSZ + b) * TT + t] = f2b(acc[m][n][r]);
      }
}

// ----------------------------------------------------------------- DFSMN stage
// E = Din @ W (via Wt rows [s][t]), A = softmax_b(E), Mn = Din*A + Mprev,
// Dout = Din + Mn.  BM=64 (batch), BN=256 (s), BK=64. Both tiles via gload_lds.
template <int FIRST>
__global__ __launch_bounds__(256) void stage_kernel(
    const unsigned short* __restrict__ Din,
    const unsigned short* __restrict__ Wt,
    unsigned short* __restrict__ M,
    unsigned short* __restrict__ Dout)
{
  __shared__ __align__(16) unsigned short Al[64 * 64];    // 8 KB linear+swz
  __shared__ __align__(16) unsigned short Bl[256 * 64];   // 32 KB linear+swz
  const int tid = threadIdx.x, w = tid >> 6, l = tid & 63;
  const int o = blockIdx.y, s0 = blockIdx.x * 256, r0 = o * BSZ;
  const unsigned short* DinR = Din + (size_t)r0 * TT;
  const unsigned short* WtR  = Wt + (size_t)s0 * TT;

  f32x4 acc[4][4];
#pragma unroll
  for (int m = 0; m < 4; ++m)
#pragma unroll
    for (int n = 0; n < 4; ++n) acc[m][n] = f32x4{0.f, 0.f, 0.f, 0.f};

  for (int k0 = 0; k0 < TT; k0 += 64) {
#pragma unroll
    for (int c = 0; c < 2; ++c) {           // A: 8 chunks, 2/wave
      int ob = (w * 2 + c) * 1024;
      int off = ob + l * 16;
      int row = off >> 7, c16 = (off >> 4) & 7;
      gload16((const char*)DinR + ((size_t)row * TT + k0) * 2 + ((c16 ^ (row & 7)) * 16),
              (char*)Al + ob);
    }
#pragma unroll
    for (int c = 0; c < 8; ++c) {           // B: 32 chunks, 8/wave
      int ob = (w * 8 + c) * 1024;
      int off = ob + l * 16;
      int row = off >> 7, c16 = (off >> 4) & 7;
      gload16((const char*)WtR + ((size_t)row * TT + k0) * 2 + ((c16 ^ (row & 7)) * 16),
              (char*)Bl + ob);
    }
    __syncthreads();
#pragma unroll
    for (int kk = 0; kk < 2; ++kk) {
      const int q = l >> 4;
      short8 a[4], bfr[4];
#pragma unroll
      for (int m = 0; m < 4; ++m) {
        int row = m * 16 + (l & 15);
        a[m] = *(const short8*)&Al[row * 64 + (((kk * 4 + q) ^ (row & 7)) * 8)];
      }
#pragma unroll
      for (int n = 0; n < 4; ++n) {
        int row = w * 64 + n * 16 + (l & 15);
        bfr[n] = *(const short8*)&Bl[row * 64 + (((kk * 4 + q) ^ (row & 7)) * 8)];
      }
#pragma unroll
      for (int m = 0; m < 4; ++m)
#pragma unroll
        for (int n = 0; n < 4; ++n)
          acc[m][n] = __builtin_amdgcn_mfma_f32_16x16x32_bf16(a[m], bfr[n], acc[m][n], 0, 0, 0);
    }
    __syncthreads();
  }

  // fused epilogue: softmax over 64 batch rows per column + gated memory
#pragma unroll
  for (int n = 0; n < 4; ++n) {
    float mx = -3.0e38f;
#pragma unroll
    for (int m = 0; m < 4; ++m)
#pragma unroll
      for (int r = 0; r < 4; ++r) mx = fmaxf(mx, acc[m][n][r]);
    mx = fmaxf(mx, __shfl_xor(mx, 16));
    mx = fmaxf(mx, __shfl_xor(mx, 32));
    float sm = 0.0f;
#pragma unroll
    for (int m = 0; m < 4; ++m)
#pragma unroll
      for (int r = 0; r < 4; ++r) sm += __expf(acc[m][n][r] - mx);
    sm += __shfl_xor(sm, 16);
    sm += __shfl_xor(sm, 32);
    const float rs = 1.0f / sm;
    const int col = s0 + w * 64 + n * 16 + (l & 15);
#pragma unroll
    for (int m = 0; m < 4; ++m)
#pragma unroll
      for (int r = 0; r < 4; ++r) {
        int row = m * 16 + (l >> 4) * 4 + r;    // b index
        size_t idx = (size_t)(r0 + row) * TT + col;
        float a  = __expf(acc[m][n][r] - mx) * rs;
        float d  = b2f(Din[idx]);
        float mp = FIRST ? 0.0f : b2f(M[idx]);
        float mn = fmaf(d, a, mp);
        float dn = d + mn;
        M[idx]    = f2b(mn);
        Dout[idx] = f2b(dn);
      }
  }
}

// ---------------------------------------------------------------- output proj
__global__ __launch_bounds__(256) void out_proj(
    const unsigned short* __restrict__ D4, const float* __restrict__ W2,
    const float* __restrict__ Bb, float* __restrict__ Y)
{
  const int r = blockIdx.x;          // o*64 + b
  const int o = r >> 6, b = r & 63;
  const int tid = threadIdx.x;
  float p0 = 0.f, p1 = 0.f, p2 = 0.f;
  for (int t = tid; t < TT; t += 256) {
    float d = b2f(D4[(size_t)r * TT + t]);
    p0 = fmaf(d, W2[t * 3 + 0], p0);
    p1 = fmaf(d, W2[t * 3 + 1], p1);
    p2 = fmaf(d, W2[t * 3 + 2], p2);
  }
#pragma unroll
  for (int off = 1; off < 64; off <<= 1) {
    p0 += __shfl_xor(p0, off);
    p1 += __shfl_xor(p1, off);
    p2 += __shfl_xor(p2, off);
  }
  __shared__ float red[4][3];
  const int w = tid >> 6, l = tid & 63;
  if (l == 0) { red[w][0] = p0; red[w][1] = p1; red[w][2] = p2; }
  __syncthreads();
  if (tid < 3) {
    float s = red[0][tid] + red[1][tid] + red[2][tid] + red[3][tid];
    Y[(size_t)(b * DD1 + o) * DD2 + tid] = s + Bb[o * DD2 + tid];
  }
}

// -------------------------------------------------------------------- launch
extern "C" void kernel_launch(void* const* d_in, const int* in_sizes, int n_in,
                              void* d_out, int out_size, void* d_ws, size_t ws_size,
                              hipStream_t stream)
{
  const float* X  = (const float*)d_in[0];
  const float* W1 = (const float*)d_in[1];
  const float* DW[4] = {(const float*)d_in[2], (const float*)d_in[3],
                        (const float*)d_in[4], (const float*)d_in[5]};
  const float* W2 = (const float*)d_in[6];
  const float* Bb = (const float*)d_in[7];
  float* Y = (float*)d_out;

  unsigned short* ws = (unsigned short*)d_ws;
  unsigned short* Wt[4];
  for (int i = 0; i < 4; ++i) Wt[i] = ws + (size_t)i * TT * TT;          // 32 MiB
  unsigned short* Dbuf0 = ws + (size_t)4 * TT * TT;                      // +32M
  unsigned short* Xt    = Dbuf0 + (size_t)NROW * TT;                     // +64M (64 MiB)
  unsigned short* Dbuf1 = Xt;                                            // alias (Xt dead after proj)
  unsigned short* Mbuf  = Xt + (size_t)NROW * TT;                        // +96M
  // peak live: proj {Wt,Xt,Dbuf0} = 128 MiB; stages {Wt,D0,D1,M} = 128 MiB

  dim3 blk(256);
  for (int i = 0; i < 4; ++i)
    transpose_cvt<<<dim3(TT / 64, TT / 64, 1), blk, 0, stream>>>(DW[i], Wt[i], TT, TT, 0, 0);
  transpose_cvt<<<dim3(TT / 64, DD0 / 64, BSZ), blk, 0, stream>>>(
      X, Xt, DD0, TT, (long)DD0 * TT, (long)TT * DD0);

  proj_kernel<<<dim3(TT / 128, BSZ), blk, 0, stream>>>(W1, Xt, Dbuf0);

  stage_kernel<1><<<dim3(TT / 256, DD1), blk, 0, stream>>>(Dbuf0, Wt[0], Mbuf, Dbuf1);
  stage_kernel<0><<<dim3(TT / 256, DD1), blk, 0, stream>>>(Dbuf1, Wt[1], Mbuf, Dbuf0);
  stage_kernel<0><<<dim3(TT / 256, DD1), blk, 0, stream>>>(Dbuf0, Wt[2], Mbuf, Dbuf1);
  stage_kernel<0><<<dim3(TT / 256, DD1), blk, 0, stream>>>(Dbuf1, Wt[3], Mbuf, Dbuf0);

  out_proj<<<dim3(NROW), blk, 0, stream>>>(Dbuf0, W2, Bb, Y);
}

// Round 3
// 502.987 us; speedup vs baseline: 1.7280x; 1.6269x over previous
//
#include <hip/hip_runtime.h>

#define TT   2048
#define BSZ  64
#define DD0  256
#define DD1  128
#define DD2  3
#define NROW (DD1*BSZ)   // 8192 rows, r = o*64 + b

typedef __attribute__((ext_vector_type(8))) short short8;
typedef __attribute__((ext_vector_type(4))) float f32x4;
typedef __attribute__((ext_vector_type(4))) unsigned short us4;

__device__ __forceinline__ unsigned short f2b(float f) {
  unsigned u = __builtin_bit_cast(unsigned, f);
  unsigned r = (u + 0x7fffu + ((u >> 16) & 1u)) >> 16;   // RNE
  return (unsigned short)r;
}
__device__ __forceinline__ float b2f(unsigned short s) {
  unsigned u = ((unsigned)s) << 16;
  return __builtin_bit_cast(float, u);
}

// async global->LDS, 16B/lane. LDS ptr = WAVE-UNIFORM base; HW writes base+lane*16.
__device__ __forceinline__ void gload16(const void* g, void* l) {
  __builtin_amdgcn_global_load_lds(
      (const __attribute__((address_space(1))) unsigned int*)(unsigned long long)g,
      (__attribute__((address_space(3))) unsigned int*)(unsigned int)(unsigned long long)l,
      16, 0, 0);
}

// ------------------------------------------------------- transpose + f32->bf16
__global__ __launch_bounds__(256) void transpose_cvt(
    const float* __restrict__ src, unsigned short* __restrict__ dst,
    int R, int C, long sstride, long dstride)
{
  __shared__ float tile[64 * 65];
  const int z = blockIdx.z;
  src += (size_t)z * sstride;
  dst += (size_t)z * dstride;
  const int c0 = blockIdx.x * 64, r0 = blockIdx.y * 64;
  const int tid = threadIdx.x;
#pragma unroll
  for (int i = 0; i < 4; ++i) {
    int e = i * 256 + tid;
    int r = e >> 4, q = e & 15;
    float4 v = *(const float4*)&src[(size_t)(r0 + r) * C + c0 + q * 4];
    tile[r * 65 + q * 4 + 0] = v.x;
    tile[r * 65 + q * 4 + 1] = v.y;
    tile[r * 65 + q * 4 + 2] = v.z;
    tile[r * 65 + q * 4 + 3] = v.w;
  }
  __syncthreads();
#pragma unroll
  for (int i = 0; i < 4; ++i) {
    int e = i * 256 + tid;
    int c = e >> 4, q = e & 15;
    us4 o;
    o[0] = f2b(tile[(q * 4 + 0) * 65 + c]);
    o[1] = f2b(tile[(q * 4 + 1) * 65 + c]);
    o[2] = f2b(tile[(q * 4 + 2) * 65 + c]);
    o[3] = f2b(tile[(q * 4 + 3) * 65 + c]);
    *(us4*)&dst[(size_t)(c0 + c) * R + r0 + q * 4] = o;
  }
}

// ------------------------------------------------------------------ projection
// Dout[(o*64+b)*T + t] = bf16( sum_d W1[o][d] * Xt[b][t][d] )
__global__ __launch_bounds__(256) void proj_kernel(
    const float* __restrict__ W1, const unsigned short* __restrict__ Xt,
    unsigned short* __restrict__ Dout)
{
  __shared__ __align__(16) unsigned short Al[128 * 72];
  __shared__ __align__(16) unsigned short Bl[128 * 64];
  const int tid = threadIdx.x;
  const int b = blockIdx.y, t0 = blockIdx.x * 128;
  const int w = tid >> 6, l = tid & 63;
  const unsigned short* XtB = Xt + ((size_t)b * TT + t0) * DD0;

  f32x4 acc[8][2];
#pragma unroll
  for (int m = 0; m < 8; ++m)
#pragma unroll
    for (int n = 0; n < 2; ++n) acc[m][n] = f32x4{0.f, 0.f, 0.f, 0.f};

  for (int k0 = 0; k0 < DD0; k0 += 64) {
#pragma unroll
    for (int i = 0; i < 4; ++i) {
      int u = i * 256 + tid;
      int row = u >> 3, cg = u & 7;
      const float* s = &W1[row * DD0 + k0 + cg * 8];
      float4 v0 = *(const float4*)s;
      float4 v1 = *(const float4*)(s + 4);
      short8 p;
      p[0] = f2b(v0.x); p[1] = f2b(v0.y); p[2] = f2b(v0.z); p[3] = f2b(v0.w);
      p[4] = f2b(v1.x); p[5] = f2b(v1.y); p[6] = f2b(v1.z); p[7] = f2b(v1.w);
      *(short8*)&Al[row * 72 + cg * 8] = p;
    }
#pragma unroll
    for (int c = 0; c < 4; ++c) {
      int ob = (w * 4 + c) * 1024;
      int off = ob + l * 16;
      int row = off >> 7, c16 = (off >> 4) & 7;
      gload16((const char*)XtB + ((size_t)row * DD0 + k0) * 2 + ((c16 ^ (row & 7)) * 16),
              (char*)Bl + ob);
    }
    __syncthreads();
#pragma unroll
    for (int kk = 0; kk < 2; ++kk) {
      const int q = l >> 4;
      short8 bfr[2];
#pragma unroll
      for (int n = 0; n < 2; ++n) {
        int row = w * 32 + n * 16 + (l & 15);
        int c16 = (kk * 4 + q) ^ (row & 7);
        bfr[n] = *(const short8*)&Bl[row * 64 + c16 * 8];
      }
#pragma unroll
      for (int m = 0; m < 8; ++m) {
        int row = m * 16 + (l & 15);
        short8 a = *(const short8*)&Al[row * 72 + (kk * 4 + q) * 8];
        acc[m][0] = __builtin_amdgcn_mfma_f32_16x16x32_bf16(a, bfr[0], acc[m][0], 0, 0, 0);
        acc[m][1] = __builtin_amdgcn_mfma_f32_16x16x32_bf16(a, bfr[1], acc[m][1], 0, 0, 0);
      }
    }
    __syncthreads();
  }
#pragma unroll
  for (int m = 0; m < 8; ++m)
#pragma unroll
    for (int n = 0; n < 2; ++n)
#pragma unroll
      for (int r = 0; r < 4; ++r) {
        int o = m * 16 + (l >> 4) * 4 + r;
        int t = t0 + w * 32 + n * 16 + (l & 15);
        Dout[(size_t)(o * BSZ + b) * TT + t] = f2b(acc[m][n][r]);
      }
}

// ----------------------------------------------------------------- DFSMN stage
// E = Din @ W (Wt rows [s][t]), A = softmax_b(E), Mn = Din*A + Mprev, Dout = Din+Mn
// BM=128 (o-pair), BN=256, BK=64; 512 thr = 8 waves (2M x 4N); double-buffered
// LDS, 2-phase: STAGE(next) -> ds_read(cur)+MFMA -> syncthreads (vmcnt drain).
template <int FIRST>
__global__ __launch_bounds__(512, 2) void stage_kernel(
    const unsigned short* __restrict__ Din,
    const unsigned short* __restrict__ Wt,
    unsigned short* __restrict__ M,
    unsigned short* __restrict__ Dout)
{
  __shared__ __align__(16) unsigned short Al[2][128 * 64];   // 2 x 16 KB
  __shared__ __align__(16) unsigned short Bl[2][256 * 64];   // 2 x 32 KB
  const int tid = threadIdx.x, w = tid >> 6, l = tid & 63;
  const int wr = w >> 2, wc = w & 3;
  const int s0 = blockIdx.x * 256, r0 = blockIdx.y * 128;
  const unsigned short* DinR = Din + (size_t)r0 * TT;
  const unsigned short* WtR  = Wt + (size_t)s0 * TT;

  f32x4 acc[4][4];
#pragma unroll
  for (int m = 0; m < 4; ++m)
#pragma unroll
    for (int n = 0; n < 4; ++n) acc[m][n] = f32x4{0.f, 0.f, 0.f, 0.f};

  const int lr = l >> 3;            // sub-row within chunk (0..7)
  const int lc = l & 7;             // 16B unit within row
  const int swzg = (lc ^ lr) << 4;  // pre-swizzled global byte offset

  // ---- prologue: stage k0=0 into buf 0
  {
#pragma unroll
    for (int c = 0; c < 2; ++c) {
      int ch = w * 2 + c;
      gload16((const char*)(DinR + (size_t)(ch * 8 + lr) * TT) + swzg,
              (char*)&Al[0][ch * 512]);
    }
#pragma unroll
    for (int c = 0; c < 4; ++c) {
      int ch = w * 4 + c;
      gload16((const char*)(WtR + (size_t)(ch * 8 + lr) * TT) + swzg,
              (char*)&Bl[0][ch * 512]);
    }
  }
  __syncthreads();

  int cur = 0;
#pragma unroll 1
  for (int t = 0; t < TT / 64; ++t) {
    if (t < TT / 64 - 1) {          // stage next tile into buf cur^1
      const int k0 = (t + 1) * 64;
#pragma unroll
      for (int c = 0; c < 2; ++c) {
        int ch = w * 2 + c;
        gload16((const char*)(DinR + (size_t)(ch * 8 + lr) * TT + k0) + swzg,
                (char*)&Al[cur ^ 1][ch * 512]);
      }
#pragma unroll
      for (int c = 0; c < 4; ++c) {
        int ch = w * 4 + c;
        gload16((const char*)(WtR + (size_t)(ch * 8 + lr) * TT + k0) + swzg,
                (char*)&Bl[cur ^ 1][ch * 512]);
      }
    }
    // compute on buf cur
#pragma unroll
    for (int kk = 0; kk < 2; ++kk) {
      const int swz = ((kk * 4 + (l >> 4)) ^ lc) * 8;   // frag-row&7 == l&7
      short8 a[4], bfr[4];
#pragma unroll
      for (int m = 0; m < 4; ++m)
        a[m] = *(const short8*)&Al[cur][(wr * 64 + m * 16 + (l & 15)) * 64 + swz];
#pragma unroll
      for (int n = 0; n < 4; ++n)
        bfr[n] = *(const short8*)&Bl[cur][(wc * 64 + n * 16 + (l & 15)) * 64 + swz];
#pragma unroll
      for (int m = 0; m < 4; ++m)
#pragma unroll
        for (int n = 0; n < 4; ++n)
          acc[m][n] = __builtin_amdgcn_mfma_f32_16x16x32_bf16(a[m], bfr[n], acc[m][n], 0, 0, 0);
    }
    __syncthreads();                // drains vmcnt(0): prefetch landed
    cur ^= 1;
  }

  // ---- fused epilogue: softmax over 64 batch rows per column + gated memory
#pragma unroll
  for (int n = 0; n < 4; ++n) {
    float mx = -3.0e38f;
#pragma unroll
    for (int m = 0; m < 4; ++m)
#pragma unroll
      for (int r = 0; r < 4; ++r) mx = fmaxf(mx, acc[m][n][r]);
    mx = fmaxf(mx, __shfl_xor(mx, 16));
    mx = fmaxf(mx, __shfl_xor(mx, 32));
    float p[4][4];
    float sm = 0.0f;
#pragma unroll
    for (int m = 0; m < 4; ++m)
#pragma unroll
      for (int r = 0; r < 4; ++r) { p[m][r] = __expf(acc[m][n][r] - mx); sm += p[m][r]; }
    sm += __shfl_xor(sm, 16);
    sm += __shfl_xor(sm, 32);
    const float rs = 1.0f / sm;
    const int col = s0 + wc * 64 + n * 16 + (l & 15);
#pragma unroll
    for (int m = 0; m < 4; ++m)
#pragma unroll
      for (int r = 0; r < 4; ++r) {
        int row = wr * 64 + m * 16 + (l >> 4) * 4 + r;   // (o-group, b)
        size_t idx = (size_t)(r0 + row) * TT + col;
        float a  = p[m][r] * rs;
        float d  = b2f(Din[idx]);
        float mp = FIRST ? 0.0f : b2f(M[idx]);
        float mn = fmaf(d, a, mp);
        float dn = d + mn;
        M[idx]    = f2b(mn);
        Dout[idx] = f2b(dn);
      }
  }
}

// ---------------------------------------------------------------- output proj
__global__ __launch_bounds__(256) void out_proj(
    const unsigned short* __restrict__ D4, const float* __restrict__ W2,
    const float* __restrict__ Bb, float* __restrict__ Y)
{
  const int r = blockIdx.x;          // o*64 + b
  const int o = r >> 6, b = r & 63;
  const int tid = threadIdx.x;
  float p0 = 0.f, p1 = 0.f, p2 = 0.f;
  for (int t = tid; t < TT; t += 256) {
    float d = b2f(D4[(size_t)r * TT + t]);
    p0 = fmaf(d, W2[t * 3 + 0], p0);
    p1 = fmaf(d, W2[t * 3 + 1], p1);
    p2 = fmaf(d, W2[t * 3 + 2], p2);
  }
#pragma unroll
  for (int off = 1; off < 64; off <<= 1) {
    p0 += __shfl_xor(p0, off);
    p1 += __shfl_xor(p1, off);
    p2 += __shfl_xor(p2, off);
  }
  __shared__ float red[4][3];
  const int w = tid >> 6, l = tid & 63;
  if (l == 0) { red[w][0] = p0; red[w][1] = p1; red[w][2] = p2; }
  __syncthreads();
  if (tid < 3) {
    float s = red[0][tid] + red[1][tid] + red[2][tid] + red[3][tid];
    Y[(size_t)(b * DD1 + o) * DD2 + tid] = s + Bb[o * DD2 + tid];
  }
}

// -------------------------------------------------------------------- launch
extern "C" void kernel_launch(void* const* d_in, const int* in_sizes, int n_in,
                              void* d_out, int out_size, void* d_ws, size_t ws_size,
                              hipStream_t stream)
{
  const float* X  = (const float*)d_in[0];
  const float* W1 = (const float*)d_in[1];
  const float* DW[4] = {(const float*)d_in[2], (const float*)d_in[3],
                        (const float*)d_in[4], (const float*)d_in[5]};
  const float* W2 = (const float*)d_in[6];
  const float* Bb = (const float*)d_in[7];
  float* Y = (float*)d_out;

  unsigned short* ws = (unsigned short*)d_ws;
  unsigned short* Wt[4];
  for (int i = 0; i < 4; ++i) Wt[i] = ws + (size_t)i * TT * TT;          // 32 MiB
  unsigned short* Dbuf0 = ws + (size_t)4 * TT * TT;                      // +32M
  unsigned short* Xt    = Dbuf0 + (size_t)NROW * TT;                     // +64M
  unsigned short* Dbuf1 = Xt;                                            // alias
  unsigned short* Mbuf  = Xt + (size_t)NROW * TT;                        // +96M

  dim3 blk(256);
  for (int i = 0; i < 4; ++i)
    transpose_cvt<<<dim3(TT / 64, TT / 64, 1), blk, 0, stream>>>(DW[i], Wt[i], TT, TT, 0, 0);
  transpose_cvt<<<dim3(TT / 64, DD0 / 64, BSZ), blk, 0, stream>>>(
      X, Xt, DD0, TT, (long)DD0 * TT, (long)TT * DD0);

  proj_kernel<<<dim3(TT / 128, BSZ), blk, 0, stream>>>(W1, Xt, Dbuf0);

  dim3 sblk(512);
  stage_kernel<1><<<dim3(TT / 256, DD1 / 2), sblk, 0, stream>>>(Dbuf0, Wt[0], Mbuf, Dbuf1);
  stage_kernel<0><<<dim3(TT / 256, DD1 / 2), sblk, 0, stream>>>(Dbuf1, Wt[1], Mbuf, Dbuf0);
  stage_kernel<0><<<dim3(TT / 256, DD1 / 2), sblk, 0, stream>>>(Dbuf0, Wt[2], Mbuf, Dbuf1);
  stage_kernel<0><<<dim3(TT / 256, DD1 / 2), sblk, 0, stream>>>(Dbuf1, Wt[3], Mbuf, Dbuf0);

  out_proj<<<dim3(NROW), blk, 0, stream>>>(Dbuf0, W2, Bb, Y);
}

// Round 5
// 437.054 us; speedup vs baseline: 1.9886x; 1.1509x over previous
//
#include <hip/hip_runtime.h>

#define TT   2048
#define BSZ  64
#define DD0  256
#define DD1  128
#define DD2  3
#define NROW (DD1*BSZ)   // 8192 rows, r = o*64 + b

typedef __attribute__((ext_vector_type(8))) short short8;
typedef __attribute__((ext_vector_type(4))) float f32x4;
typedef __attribute__((ext_vector_type(4))) unsigned short us4;

__device__ __forceinline__ unsigned short f2b(float f) {
  unsigned u = __builtin_bit_cast(unsigned, f);
  unsigned r = (u + 0x7fffu + ((u >> 16) & 1u)) >> 16;   // RNE
  return (unsigned short)r;
}
__device__ __forceinline__ float b2f(unsigned short s) {
  unsigned u = ((unsigned)s) << 16;
  return __builtin_bit_cast(float, u);
}

// async global->LDS, 16B/lane. LDS ptr = WAVE-UNIFORM base; HW writes base+lane*16.
__device__ __forceinline__ void gload16(const void* g, void* l) {
  __builtin_amdgcn_global_load_lds(
      (const __attribute__((address_space(1))) unsigned int*)(unsigned long long)g,
      (__attribute__((address_space(3))) unsigned int*)(unsigned int)(unsigned long long)l,
      16, 0, 0);
}

// ------------------------------------------------------- transpose + f32->bf16
__global__ __launch_bounds__(256) void transpose_cvt(
    const float* __restrict__ src, unsigned short* __restrict__ dst,
    int R, int C, long sstride, long dstride)
{
  __shared__ float tile[64 * 65];
  const int z = blockIdx.z;
  src += (size_t)z * sstride;
  dst += (size_t)z * dstride;
  const int c0 = blockIdx.x * 64, r0 = blockIdx.y * 64;
  const int tid = threadIdx.x;
#pragma unroll
  for (int i = 0; i < 4; ++i) {
    int e = i * 256 + tid;
    int r = e >> 4, q = e & 15;
    float4 v = *(const float4*)&src[(size_t)(r0 + r) * C + c0 + q * 4];
    tile[r * 65 + q * 4 + 0] = v.x;
    tile[r * 65 + q * 4 + 1] = v.y;
    tile[r * 65 + q * 4 + 2] = v.z;
    tile[r * 65 + q * 4 + 3] = v.w;
  }
  __syncthreads();
#pragma unroll
  for (int i = 0; i < 4; ++i) {
    int e = i * 256 + tid;
    int c = e >> 4, q = e & 15;
    us4 o;
    o[0] = f2b(tile[(q * 4 + 0) * 65 + c]);
    o[1] = f2b(tile[(q * 4 + 1) * 65 + c]);
    o[2] = f2b(tile[(q * 4 + 2) * 65 + c]);
    o[3] = f2b(tile[(q * 4 + 3) * 65 + c]);
    *(us4*)&dst[(size_t)(c0 + c) * R + r0 + q * 4] = o;
  }
}

// ------------------------------------------------------------------ projection
__global__ __launch_bounds__(256) void proj_kernel(
    const float* __restrict__ W1, const unsigned short* __restrict__ Xt,
    unsigned short* __restrict__ Dout)
{
  __shared__ __align__(16) unsigned short Al[128 * 72];
  __shared__ __align__(16) unsigned short Bl[128 * 64];
  const int tid = threadIdx.x;
  const int b = blockIdx.y, t0 = blockIdx.x * 128;
  const int w = tid >> 6, l = tid & 63;
  const unsigned short* XtB = Xt + ((size_t)b * TT + t0) * DD0;

  f32x4 acc[8][2];
#pragma unroll
  for (int m = 0; m < 8; ++m)
#pragma unroll
    for (int n = 0; n < 2; ++n) acc[m][n] = f32x4{0.f, 0.f, 0.f, 0.f};

  for (int k0 = 0; k0 < DD0; k0 += 64) {
#pragma unroll
    for (int i = 0; i < 4; ++i) {
      int u = i * 256 + tid;
      int row = u >> 3, cg = u & 7;
      const float* s = &W1[row * DD0 + k0 + cg * 8];
      float4 v0 = *(const float4*)s;
      float4 v1 = *(const float4*)(s + 4);
      short8 p;
      p[0] = f2b(v0.x); p[1] = f2b(v0.y); p[2] = f2b(v0.z); p[3] = f2b(v0.w);
      p[4] = f2b(v1.x); p[5] = f2b(v1.y); p[6] = f2b(v1.z); p[7] = f2b(v1.w);
      *(short8*)&Al[row * 72 + cg * 8] = p;
    }
#pragma unroll
    for (int c = 0; c < 4; ++c) {
      int ob = (w * 4 + c) * 1024;
      int off = ob + l * 16;
      int row = off >> 7, c16 = (off >> 4) & 7;
      gload16((const char*)XtB + ((size_t)row * DD0 + k0) * 2 + ((c16 ^ (row & 7)) * 16),
              (char*)Bl + ob);
    }
    __syncthreads();
#pragma unroll
    for (int kk = 0; kk < 2; ++kk) {
      const int q = l >> 4;
      short8 bfr[2];
#pragma unroll
      for (int n = 0; n < 2; ++n) {
        int row = w * 32 + n * 16 + (l & 15);
        int c16 = (kk * 4 + q) ^ (row & 7);
        bfr[n] = *(const short8*)&Bl[row * 64 + c16 * 8];
      }
#pragma unroll
      for (int m = 0; m < 8; ++m) {
        int row = m * 16 + (l & 15);
        short8 a = *(const short8*)&Al[row * 72 + (kk * 4 + q) * 8];
        acc[m][0] = __builtin_amdgcn_mfma_f32_16x16x32_bf16(a, bfr[0], acc[m][0], 0, 0, 0);
        acc[m][1] = __builtin_amdgcn_mfma_f32_16x16x32_bf16(a, bfr[1], acc[m][1], 0, 0, 0);
      }
    }
    __syncthreads();
  }
#pragma unroll
  for (int m = 0; m < 8; ++m)
#pragma unroll
    for (int n = 0; n < 2; ++n)
#pragma unroll
      for (int r = 0; r < 4; ++r) {
        int o = m * 16 + (l >> 4) * 4 + r;
        int t = t0 + w * 32 + n * 16 + (l & 15);
        Dout[(size_t)(o * BSZ + b) * TT + t] = f2b(acc[m][n][r]);
      }
}

// ----------------------------------------------------------------- DFSMN stage
// BM=256 (4 o-groups), BN=256, BK=64; 512 thr = 8 waves (2Mx4N), 128x64/wave.
// Counted-vmcnt pipeline: never drain to 0 mid-loop (8 loads/wave/K-tile).
template <int FIRST>
__global__ __launch_bounds__(512, 2) void stage_kernel(
    const unsigned short* __restrict__ Din,
    const unsigned short* __restrict__ Wt,
    unsigned short* __restrict__ M,
    unsigned short* __restrict__ Dout)
{
  __shared__ __align__(16) unsigned short lds[65536];   // 128 KiB
  const int tid = threadIdx.x, w = tid >> 6, l = tid & 63;
  const int wr = w >> 2, wc = w & 3;
  const int s0 = blockIdx.x * 256, r0 = blockIdx.y * 256;
  const unsigned short* DinR = Din + (size_t)r0 * TT;
  const unsigned short* WtR  = Wt + (size_t)s0 * TT;
  const int lr = l >> 3, lc = l & 7;
  const int swzg = (lc ^ lr) << 4;          // pre-swizzled global byte offset
  const int NT = TT / 64;                   // 32 K-tiles

  f32x4 acc[8][4];
#pragma unroll
  for (int m = 0; m < 8; ++m)
#pragma unroll
    for (int n = 0; n < 4; ++n) acc[m][n] = f32x4{0.f, 0.f, 0.f, 0.f};

  // A(p) at lds+p*16384, B(p) at lds+32768+p*16384 (ushort units)
  auto STAGE = [&](int tile) {              // 8 gload_lds per lane
    const int k0 = tile * 64;
    char* Ad = (char*)&lds[(tile & 1) * 16384];
    char* Bd = (char*)&lds[32768 + (tile & 1) * 16384];
#pragma unroll
    for (int c = 0; c < 4; ++c) {
      int ch = w * 4 + c;                   // 1KB chunk = 8 rows x 128B
      gload16((const char*)(DinR + (size_t)(ch * 8 + lr) * TT + k0) + swzg,
              Ad + ch * 1024);
      gload16((const char*)(WtR + (size_t)(ch * 8 + lr) * TT + k0) + swzg,
              Bd + ch * 1024);
    }
  };

  STAGE(0);
  STAGE(1);

#pragma unroll 1
  for (int t = 0; t < NT; ++t) {
    if (t == NT - 1) asm volatile("s_waitcnt vmcnt(0)" ::: "memory");
    else             asm volatile("s_waitcnt vmcnt(8)" ::: "memory");
    __builtin_amdgcn_s_barrier();           // tile t resident in buf[t&1]
    const unsigned short* Ab = &lds[(t & 1) * 16384];
    const unsigned short* Bb = &lds[32768 + (t & 1) * 16384];
    __builtin_amdgcn_s_setprio(1);
#pragma unroll
    for (int kk = 0; kk < 2; ++kk) {
      const int swz = ((kk * 4 + (l >> 4)) ^ lc) * 8;   // frag row&7 == l&7
      short8 a[8], bfr[4];
#pragma unroll
      for (int m = 0; m < 8; ++m)
        a[m] = *(const short8*)&Ab[(wr * 128 + m * 16 + (l & 15)) * 64 + swz];
#pragma unroll
      for (int n = 0; n < 4; ++n)
        bfr[n] = *(const short8*)&Bb[(wc * 64 + n * 16 + (l & 15)) * 64 + swz];
#pragma unroll
      for (int m = 0; m < 8; ++m)
#pragma unroll
        for (int n = 0; n < 4; ++n)
          acc[m][n] = __builtin_amdgcn_mfma_f32_16x16x32_bf16(a[m], bfr[n], acc[m][n], 0, 0, 0);
    }
    __builtin_amdgcn_s_setprio(0);
    asm volatile("" ::: "memory");
    __builtin_amdgcn_s_barrier();           // all waves done reading buf[t&1]
    if (t < NT - 2) STAGE(t + 2);           // overwrite buf[t&1]; stays in flight
  }

  // ---- epilogue 1: softmax over each 64-batch group, stage probs (bf16) in LDS
  const int q = l >> 4, cc = l & 15;
#pragma unroll
  for (int n = 0; n < 4; ++n) {
#pragma unroll
    for (int g = 0; g < 2; ++g) {           // g=0: rows 0-63 of stripe, g=1: 64-127
      float mx = -3.0e38f;
#pragma unroll
      for (int m = 0; m < 4; ++m)
#pragma unroll
        for (int r = 0; r < 4; ++r) mx = fmaxf(mx, acc[g * 4 + m][n][r]);
      mx = fmaxf(mx, __shfl_xor(mx, 16));
      mx = fmaxf(mx, __shfl_xor(mx, 32));
      float pr[4][4];
      float sm = 0.f;
#pragma unroll
      for (int m = 0; m < 4; ++m)
#pragma unroll
        for (int r = 0; r < 4; ++r) { pr[m][r] = __expf(acc[g * 4 + m][n][r] - mx); sm += pr[m][r]; }
      sm += __shfl_xor(sm, 16);
      sm += __shfl_xor(sm, 32);
      const float rs = 1.f / sm;
      const int col = wc * 64 + n * 16 + cc;
      const int u = col >> 3;
#pragma unroll
      for (int m = 0; m < 4; ++m)
#pragma unroll
        for (int r = 0; r < 4; ++r) {
          int row = wr * 128 + (g * 4 + m) * 16 + q * 4 + r;
          lds[row * 256 + (((u ^ ((row >> 2) & 7)) << 3) | (col & 7))] = f2b(pr[m][r] * rs);
        }
    }
  }
  asm volatile("s_waitcnt lgkmcnt(0)" ::: "memory");
  __builtin_amdgcn_s_barrier();

  // ---- epilogue 2: fully-coalesced stream: Mn = D*A + Mprev; Dout = D + Mn
  // 256 rows x 32 short8-units = 8192 units over 512 threads -> 16 iters.
#pragma unroll 4
  for (int i = 0; i < 16; ++i) {
    int unit = i * 512 + tid;
    int row = unit >> 5, u = unit & 31;
    short8 a8 = *(const short8*)&lds[row * 256 + ((u ^ ((row >> 2) & 7)) << 3)];
    size_t g = (size_t)(r0 + row) * TT + s0 + u * 8;
    short8 d8 = *(const short8*)&Din[g];
    short8 mp8 = {};
    if (!FIRST) mp8 = *(const short8*)&M[g];
    short8 mo, dn;
#pragma unroll
    for (int j = 0; j < 8; ++j) {
      float d = b2f((unsigned short)d8[j]);
      float a = b2f((unsigned short)a8[j]);
      float mp = FIRST ? 0.f : b2f((unsigned short)mp8[j]);
      float mn = fmaf(d, a, mp);
      mo[j] = (short)f2b(mn);
      dn[j] = (short)f2b(d + mn);
    }
    *(short8*)&M[g] = mo;
    *(short8*)&Dout[g] = dn;
  }
}

// ---------------------------------------------------------------- output proj
__global__ __launch_bounds__(256) void out_proj(
    const unsigned short* __restrict__ D4, const float* __restrict__ W2,
    const float* __restrict__ Bb, float* __restrict__ Y)
{
  const int r = blockIdx.x;          // o*64 + b
  const int o = r >> 6, b = r & 63;
  const int tid = threadIdx.x;
  float p0 = 0.f, p1 = 0.f, p2 = 0.f;
  for (int t = tid; t < TT; t += 256) {
    float d = b2f(D4[(size_t)r * TT + t]);
    p0 = fmaf(d, W2[t * 3 + 0], p0);
    p1 = fmaf(d, W2[t * 3 + 1], p1);
    p2 = fmaf(d, W2[t * 3 + 2], p2);
  }
#pragma unroll
  for (int off = 1; off < 64; off <<= 1) {
    p0 += __shfl_xor(p0, off);
    p1 += __shfl_xor(p1, off);
    p2 += __shfl_xor(p2, off);
  }
  __shared__ float red[4][3];
  const int w = tid >> 6, l = tid & 63;
  if (l == 0) { red[w][0] = p0; red[w][1] = p1; red[w][2] = p2; }
  __syncthreads();
  if (tid < 3) {
    float s = red[0][tid] + red[1][tid] + red[2][tid] + red[3][tid];
    Y[(size_t)(b * DD1 + o) * DD2 + tid] = s + Bb[o * DD2 + tid];
  }
}

// -------------------------------------------------------------------- launch
extern "C" void kernel_launch(void* const* d_in, const int* in_sizes, int n_in,
                              void* d_out, int out_size, void* d_ws, size_t ws_size,
                              hipStream_t stream)
{
  const float* X  = (const float*)d_in[0];
  const float* W1 = (const float*)d_in[1];
  const float* DW[4] = {(const float*)d_in[2], (const float*)d_in[3],
                        (const float*)d_in[4], (const float*)d_in[5]};
  const float* W2 = (const float*)d_in[6];
  const float* Bb = (const float*)d_in[7];
  float* Y = (float*)d_out;

  unsigned short* ws = (unsigned short*)d_ws;
  unsigned short* Wt[4];
  for (int i = 0; i < 4; ++i) Wt[i] = ws + (size_t)i * TT * TT;          // 32 MiB
  unsigned short* Dbuf0 = ws + (size_t)4 * TT * TT;                      // +32M
  unsigned short* Xt    = Dbuf0 + (size_t)NROW * TT;                     // +64M
  unsigned short* Dbuf1 = Xt;                                            // alias
  unsigned short* Mbuf  = Xt + (size_t)NROW * TT;                        // +96M

  dim3 blk(256);
  for (int i = 0; i < 4; ++i)
    transpose_cvt<<<dim3(TT / 64, TT / 64, 1), blk, 0, stream>>>(DW[i], Wt[i], TT, TT, 0, 0);
  transpose_cvt<<<dim3(TT / 64, DD0 / 64, BSZ), blk, 0, stream>>>(
      X, Xt, DD0, TT, (long)DD0 * TT, (long)TT * DD0);

  proj_kernel<<<dim3(TT / 128, BSZ), blk, 0, stream>>>(W1, Xt, Dbuf0);

  dim3 sblk(512);
  dim3 sgrid(TT / 256, NROW / 256);
  stage_kernel<1><<<sgrid, sblk, 0, stream>>>(Dbuf0, Wt[0], Mbuf, Dbuf1);
  stage_kernel<0><<<sgrid, sblk, 0, stream>>>(Dbuf1, Wt[1], Mbuf, Dbuf0);
  stage_kernel<0><<<sgrid, sblk, 0, stream>>>(Dbuf0, Wt[2], Mbuf, Dbuf1);
  stage_kernel<0><<<sgrid, sblk, 0, stream>>>(Dbuf1, Wt[3], Mbuf, Dbuf0);

  out_proj<<<dim3(NROW), blk, 0, stream>>>(Dbuf0, W2, Bb, Y);
}

// Round 6
// 415.477 us; speedup vs baseline: 2.0919x; 1.0519x over previous
//
#include <hip/hip_runtime.h>

#define TT   2048
#define BSZ  64
#define DD0  256
#define DD1  128
#define DD2  3
#define NROW (DD1*BSZ)   // 8192 rows, r = o*64 + b

typedef __attribute__((ext_vector_type(8))) short short8;
typedef __attribute__((ext_vector_type(4))) float f32x4;
typedef __attribute__((ext_vector_type(4))) unsigned short us4;

__device__ __forceinline__ unsigned short f2b(float f) {
  unsigned u = __builtin_bit_cast(unsigned, f);
  unsigned r = (u + 0x7fffu + ((u >> 16) & 1u)) >> 16;   // RNE
  return (unsigned short)r;
}
__device__ __forceinline__ float b2f(unsigned short s) {
  unsigned u = ((unsigned)s) << 16;
  return __builtin_bit_cast(float, u);
}

// async global->LDS, 16B/lane. LDS ptr = WAVE-UNIFORM base; HW writes base+lane*16.
__device__ __forceinline__ void gload16(const void* g, void* l) {
  __builtin_amdgcn_global_load_lds(
      (const __attribute__((address_space(1))) unsigned int*)(unsigned long long)g,
      (__attribute__((address_space(3))) unsigned int*)(unsigned int)(unsigned long long)l,
      16, 0, 0);
}

// ------------------------------------------------------- transpose + f32->bf16
__global__ __launch_bounds__(256) void transpose_cvt(
    const float* __restrict__ src, unsigned short* __restrict__ dst,
    int R, int C, long sstride, long dstride)
{
  __shared__ float tile[64 * 65];
  const int z = blockIdx.z;
  src += (size_t)z * sstride;
  dst += (size_t)z * dstride;
  const int c0 = blockIdx.x * 64, r0 = blockIdx.y * 64;
  const int tid = threadIdx.x;
#pragma unroll
  for (int i = 0; i < 4; ++i) {
    int e = i * 256 + tid;
    int r = e >> 4, q = e & 15;
    float4 v = *(const float4*)&src[(size_t)(r0 + r) * C + c0 + q * 4];
    tile[r * 65 + q * 4 + 0] = v.x;
    tile[r * 65 + q * 4 + 1] = v.y;
    tile[r * 65 + q * 4 + 2] = v.z;
    tile[r * 65 + q * 4 + 3] = v.w;
  }
  __syncthreads();
#pragma unroll
  for (int i = 0; i < 4; ++i) {
    int e = i * 256 + tid;
    int c = e >> 4, q = e & 15;
    us4 o;
    o[0] = f2b(tile[(q * 4 + 0) * 65 + c]);
    o[1] = f2b(tile[(q * 4 + 1) * 65 + c]);
    o[2] = f2b(tile[(q * 4 + 2) * 65 + c]);
    o[3] = f2b(tile[(q * 4 + 3) * 65 + c]);
    *(us4*)&dst[(size_t)(c0 + c) * R + r0 + q * 4] = o;
  }
}

// ------------------------------------------------------------------ projection
__global__ __launch_bounds__(256) void proj_kernel(
    const float* __restrict__ W1, const unsigned short* __restrict__ Xt,
    unsigned short* __restrict__ Dout)
{
  __shared__ __align__(16) unsigned short Al[128 * 72];
  __shared__ __align__(16) unsigned short Bl[128 * 64];
  const int tid = threadIdx.x;
  const int b = blockIdx.y, t0 = blockIdx.x * 128;
  const int w = tid >> 6, l = tid & 63;
  const unsigned short* XtB = Xt + ((size_t)b * TT + t0) * DD0;

  f32x4 acc[8][2];
#pragma unroll
  for (int m = 0; m < 8; ++m)
#pragma unroll
    for (int n = 0; n < 2; ++n) acc[m][n] = f32x4{0.f, 0.f, 0.f, 0.f};

  for (int k0 = 0; k0 < DD0; k0 += 64) {
#pragma unroll
    for (int i = 0; i < 4; ++i) {
      int u = i * 256 + tid;
      int row = u >> 3, cg = u & 7;
      const float* s = &W1[row * DD0 + k0 + cg * 8];
      float4 v0 = *(const float4*)s;
      float4 v1 = *(const float4*)(s + 4);
      short8 p;
      p[0] = f2b(v0.x); p[1] = f2b(v0.y); p[2] = f2b(v0.z); p[3] = f2b(v0.w);
      p[4] = f2b(v1.x); p[5] = f2b(v1.y); p[6] = f2b(v1.z); p[7] = f2b(v1.w);
      *(short8*)&Al[row * 72 + cg * 8] = p;
    }
#pragma unroll
    for (int c = 0; c < 4; ++c) {
      int ob = (w * 4 + c) * 1024;
      int off = ob + l * 16;
      int row = off >> 7, c16 = (off >> 4) & 7;
      gload16((const char*)XtB + ((size_t)row * DD0 + k0) * 2 + ((c16 ^ (row & 7)) * 16),
              (char*)Bl + ob);
    }
    __syncthreads();
#pragma unroll
    for (int kk = 0; kk < 2; ++kk) {
      const int q = l >> 4;
      short8 bfr[2];
#pragma unroll
      for (int n = 0; n < 2; ++n) {
        int row = w * 32 + n * 16 + (l & 15);
        int c16 = (kk * 4 + q) ^ (row & 7);
        bfr[n] = *(const short8*)&Bl[row * 64 + c16 * 8];
      }
#pragma unroll
      for (int m = 0; m < 8; ++m) {
        int row = m * 16 + (l & 15);
        short8 a = *(const short8*)&Al[row * 72 + (kk * 4 + q) * 8];
        acc[m][0] = __builtin_amdgcn_mfma_f32_16x16x32_bf16(a, bfr[0], acc[m][0], 0, 0, 0);
        acc[m][1] = __builtin_amdgcn_mfma_f32_16x16x32_bf16(a, bfr[1], acc[m][1], 0, 0, 0);
      }
    }
    __syncthreads();
  }
#pragma unroll
  for (int m = 0; m < 8; ++m)
#pragma unroll
    for (int n = 0; n < 2; ++n)
#pragma unroll
      for (int r = 0; r < 4; ++r) {
        int o = m * 16 + (l >> 4) * 4 + r;
        int t = t0 + w * 32 + n * 16 + (l & 15);
        Dout[(size_t)(o * BSZ + b) * TT + t] = f2b(acc[m][n][r]);
      }
}

// ----------------------------------------------------------------- DFSMN stage
// BM=256, BN=256, BK=64; 512 thr = 8 waves (2Mx4N). 4-phase/K-tile interleave:
// quadrant (ah,bh) order (0,0),(0,1),(1,1),(1,0); 1 half-tile staged per phase
// (2 gload16/thread) for K-tile t+1; counted vmcnt(2) gates.
//
// Stage/consume ledger (ht e of tile τ staged at phase (τ-1,e); dist 4):
//   Ah0(τ) staged (τ-1,0) read (τ,0): gate(τ,0) lands all but newest 2 -> ok
//   Bh0(τ) staged (τ-1,1) read (τ,0)&(τ,3): gate(τ,0) newest2=(τ-1,3)'s -> landed
//   Bh1(τ) staged (τ-1,2) read (τ,1): landed at gate(τ,0) already
//   Ah1(τ) staged (τ-1,3) read (τ,2): gate(τ,1) newest2=(τ,0)'s -> landed; +barrier
// Cross-wave: every read is preceded by [other waves' gate -> shared barrier].
// Buffer overwrite: ht e of τ+1 written at (τ,e) into buf^1; prior occupant
// (τ-1) last read at (τ-1,3) -> barrier before (τ,0). Tail: vmcnt(0) at (NT-1,0).
template <int FIRST>
__global__ __launch_bounds__(512, 2) void stage_kernel(
    const unsigned short* __restrict__ Din,
    const unsigned short* __restrict__ Wt,
    unsigned short* __restrict__ M,
    unsigned short* __restrict__ Dout)
{
  __shared__ __align__(16) unsigned short lds[65536];   // A:[0,32K) B:[32K,64K) ushorts
  const int tid = threadIdx.x, w = tid >> 6, l = tid & 63;
  const int wr = w >> 2, wc = w & 3;
  // XCD chunking: xcd = linear%8 owns 8 s-tiles x 4 r-tiles
  const int L = blockIdx.y * 8 + blockIdx.x;
  const int s0 = ((L >> 3) & 7) * 256;
  const int r0 = ((L & 7) * 4 + (L >> 6)) * 256;
  const unsigned short* DinR = Din + (size_t)r0 * TT;
  const unsigned short* WtR  = Wt + (size_t)s0 * TT;
  const int q4 = l >> 4;
  const int swzg = ((l & 7) ^ (l >> 3)) << 4;   // inverse-swizzled global byte off
  const int NT = TT / 64;                       // 32 K-tiles

  f32x4 acc[8][4];                              // [ah*4+m][bh*2+n]
#pragma unroll
  for (int m = 0; m < 8; ++m)
#pragma unroll
    for (int n = 0; n < 4; ++n) acc[m][n] = f32x4{0.f, 0.f, 0.f, 0.f};

  // ht e: 0=Ah0 1=Bh0 2=Bh1 3=Ah1; half-tile = 128 rows x 64 k, 16 KB
  auto STAGE_HT = [&](int tau, int e) {
    if (tau >= NT) return;
    const int k0 = tau * 64, buf = tau & 1;
    const int isB = (e == 1 || e == 2);
    const int h = (e >= 2) ? 1 : 0;
    const unsigned short* base = isB ? WtR : DinR;
    unsigned short* ldst = &lds[(isB ? 32768 : 0) + buf * 16384 + h * 8192];
#pragma unroll
    for (int i = 0; i < 2; ++i) {
      int rr = i * 64 + w * 8 + (l >> 3);       // row within half
      gload16((const char*)(base + (size_t)(h * 128 + rr) * TT + k0) + swzg,
              (char*)ldst + (i * 512 + w * 64) * 16);
    }
  };
  auto LDA = [&](int buf, int ah, short8 (&ar)[4][2]) {
#pragma unroll
    for (int m = 0; m < 4; ++m) {
      int ra = wr * 64 + m * 16 + (l & 15);
#pragma unroll
      for (int kk = 0; kk < 2; ++kk)
        ar[m][kk] = *(const short8*)&lds[buf * 16384 + ah * 8192 + ra * 64 +
                                         (((kk * 4 + q4) ^ (ra & 7)) * 8)];
    }
  };
  auto LDB = [&](int buf, int bh, short8 (&br)[2][2]) {
#pragma unroll
    for (int n = 0; n < 2; ++n) {
      int rb = wc * 32 + n * 16 + (l & 15);
#pragma unroll
      for (int kk = 0; kk < 2; ++kk)
        br[n][kk] = *(const short8*)&lds[32768 + buf * 16384 + bh * 8192 + rb * 64 +
                                         (((kk * 4 + q4) ^ (rb & 7)) * 8)];
    }
  };
  auto MM = [&](int ah, int bh, short8 (&ar)[4][2], short8 (&br)[2][2]) {
    __builtin_amdgcn_s_setprio(1);
#pragma unroll
    for (int m = 0; m < 4; ++m)
#pragma unroll
      for (int n = 0; n < 2; ++n)
#pragma unroll
        for (int kk = 0; kk < 2; ++kk)
          acc[ah * 4 + m][bh * 2 + n] = __builtin_amdgcn_mfma_f32_16x16x32_bf16(
              ar[m][kk], br[n][kk], acc[ah * 4 + m][bh * 2 + n], 0, 0, 0);
    __builtin_amdgcn_s_setprio(0);
  };

  short8 a[4][2], b0[2][2], b1[2][2];

  // prologue: stage all 4 half-tiles of K-tile 0; land ht0-2 in every wave,
  // then barrier so cross-wave reads at (0,0) are safe.
  STAGE_HT(0, 0); STAGE_HT(0, 1); STAGE_HT(0, 2); STAGE_HT(0, 3);
  asm volatile("s_waitcnt vmcnt(2)" ::: "memory");
  __builtin_amdgcn_s_barrier();

#pragma unroll 1
  for (int t = 0; t < NT; ++t) {
    const int buf = t & 1;
    // ---- P0: quadrant (0,0)
    if (t == NT - 1) { asm volatile("s_waitcnt vmcnt(0)" ::: "memory"); }
    else             { asm volatile("s_waitcnt vmcnt(2)" ::: "memory"); }
    LDA(buf, 0, a);
    LDB(buf, 0, b0);
    STAGE_HT(t + 1, 0);
    __builtin_amdgcn_s_barrier();
    asm volatile("s_waitcnt lgkmcnt(0)" ::: "memory");
    __builtin_amdgcn_sched_barrier(0);
    MM(0, 0, a, b0);
    __builtin_amdgcn_s_barrier();
    // ---- P1: quadrant (0,1)
    asm volatile("s_waitcnt vmcnt(2)" ::: "memory");
    LDB(buf, 1, b1);
    STAGE_HT(t + 1, 1);
    __builtin_amdgcn_s_barrier();
    asm volatile("s_waitcnt lgkmcnt(0)" ::: "memory");
    __builtin_amdgcn_sched_barrier(0);
    MM(0, 1, a, b1);
    __builtin_amdgcn_s_barrier();
    // ---- P2: quadrant (1,1)
    asm volatile("s_waitcnt vmcnt(2)" ::: "memory");
    LDA(buf, 1, a);
    STAGE_HT(t + 1, 2);
    __builtin_amdgcn_s_barrier();
    asm volatile("s_waitcnt lgkmcnt(0)" ::: "memory");
    __builtin_amdgcn_sched_barrier(0);
    MM(1, 1, a, b1);
    __builtin_amdgcn_s_barrier();
    // ---- P3: quadrant (1,0), no new ds_read (b0 still live)
    STAGE_HT(t + 1, 3);
    __builtin_amdgcn_s_barrier();
    MM(1, 0, a, b0);
    __builtin_amdgcn_s_barrier();
  }

  // ---- epilogue 1: softmax over each 64-batch group, stage probs (bf16) in LDS
  const int cc = l & 15;
#pragma unroll
  for (int j = 0; j < 4; ++j) {                 // j = bh*2+n
    const int bh = j >> 1, nn = j & 1;
    const int col = bh * 128 + wc * 32 + nn * 16 + cc;
    const int u = col >> 3;
#pragma unroll
    for (int ah = 0; ah < 2; ++ah) {            // batch group = ah*2 + wr
      float mx = -3.0e38f;
#pragma unroll
      for (int m = 0; m < 4; ++m)
#pragma unroll
        for (int r = 0; r < 4; ++r) mx = fmaxf(mx, acc[ah * 4 + m][j][r]);
      mx = fmaxf(mx, __shfl_xor(mx, 16));
      mx = fmaxf(mx, __shfl_xor(mx, 32));
      float pr[4][4];
      float sm = 0.f;
#pragma unroll
      for (int m = 0; m < 4; ++m)
#pragma unroll
        for (int r = 0; r < 4; ++r) { pr[m][r] = __expf(acc[ah * 4 + m][j][r] - mx); sm += pr[m][r]; }
      sm += __shfl_xor(sm, 16);
      sm += __shfl_xor(sm, 32);
      const float rs = 1.f / sm;
#pragma unroll
      for (int m = 0; m < 4; ++m)
#pragma unroll
        for (int r = 0; r < 4; ++r) {
          int row = ah * 128 + wr * 64 + m * 16 + q4 * 4 + r;
          lds[row * 256 + (((u ^ ((row >> 2) & 7)) << 3) | (col & 7))] = f2b(pr[m][r] * rs);
        }
    }
  }
  asm volatile("s_waitcnt lgkmcnt(0)" ::: "memory");
  __builtin_amdgcn_s_barrier();

  // ---- epilogue 2: fully-coalesced stream: Mn = D*A + Mprev; Dout = D + Mn
  // 256 rows x 32 short8-units = 8192 units over 512 threads -> 16 iters.
#pragma unroll 4
  for (int i = 0; i < 16; ++i) {
    int unit = i * 512 + tid;
    int row = unit >> 5, u = unit & 31;
    short8 a8 = *(const short8*)&lds[row * 256 + ((u ^ ((row >> 2) & 7)) << 3)];
    size_t g = (size_t)(r0 + row) * TT + s0 + u * 8;
    short8 d8 = *(const short8*)&Din[g];
    short8 mp8 = {};
    if (!FIRST) mp8 = *(const short8*)&M[g];
    short8 mo, dn;
#pragma unroll
    for (int j = 0; j < 8; ++j) {
      float d = b2f((unsigned short)d8[j]);
      float aa = b2f((unsigned short)a8[j]);
      float mp = FIRST ? 0.f : b2f((unsigned short)mp8[j]);
      float mn = fmaf(d, aa, mp);
      mo[j] = (short)f2b(mn);
      dn[j] = (short)f2b(d + mn);
    }
    *(short8*)&M[g] = mo;
    *(short8*)&Dout[g] = dn;
  }
}

// ---------------------------------------------------------------- output proj
__global__ __launch_bounds__(256) void out_proj(
    const unsigned short* __restrict__ D4, const float* __restrict__ W2,
    const float* __restrict__ Bb, float* __restrict__ Y)
{
  const int r = blockIdx.x;          // o*64 + b
  const int o = r >> 6, b = r & 63;
  const int tid = threadIdx.x;
  float p0 = 0.f, p1 = 0.f, p2 = 0.f;
  for (int t = tid; t < TT; t += 256) {
    float d = b2f(D4[(size_t)r * TT + t]);
    p0 = fmaf(d, W2[t * 3 + 0], p0);
    p1 = fmaf(d, W2[t * 3 + 1], p1);
    p2 = fmaf(d, W2[t * 3 + 2], p2);
  }
#pragma unroll
  for (int off = 1; off < 64; off <<= 1) {
    p0 += __shfl_xor(p0, off);
    p1 += __shfl_xor(p1, off);
    p2 += __shfl_xor(p2, off);
  }
  __shared__ float red[4][3];
  const int w = tid >> 6, l = tid & 63;
  if (l == 0) { red[w][0] = p0; red[w][1] = p1; red[w][2] = p2; }
  __syncthreads();
  if (tid < 3) {
    float s = red[0][tid] + red[1][tid] + red[2][tid] + red[3][tid];
    Y[(size_t)(b * DD1 + o) * DD2 + tid] = s + Bb[o * DD2 + tid];
  }
}

// -------------------------------------------------------------------- launch
extern "C" void kernel_launch(void* const* d_in, const int* in_sizes, int n_in,
                              void* d_out, int out_size, void* d_ws, size_t ws_size,
                              hipStream_t stream)
{
  const float* X  = (const float*)d_in[0];
  const float* W1 = (const float*)d_in[1];
  const float* DW[4] = {(const float*)d_in[2], (const float*)d_in[3],
                        (const float*)d_in[4], (const float*)d_in[5]};
  const float* W2 = (const float*)d_in[6];
  const float* Bb = (const float*)d_in[7];
  float* Y = (float*)d_out;

  unsigned short* ws = (unsigned short*)d_ws;
  unsigned short* Wt[4];
  for (int i = 0; i < 4; ++i) Wt[i] = ws + (size_t)i * TT * TT;          // 32 MiB
  unsigned short* Dbuf0 = ws + (size_t)4 * TT * TT;                      // +32M
  unsigned short* Xt    = Dbuf0 + (size_t)NROW * TT;                     // +64M
  unsigned short* Dbuf1 = Xt;                                            // alias
  unsigned short* Mbuf  = Xt + (size_t)NROW * TT;                        // +96M

  dim3 blk(256);
  for (int i = 0; i < 4; ++i)
    transpose_cvt<<<dim3(TT / 64, TT / 64, 1), blk, 0, stream>>>(DW[i], Wt[i], TT, TT, 0, 0);
  transpose_cvt<<<dim3(TT / 64, DD0 / 64, BSZ), blk, 0, stream>>>(
      X, Xt, DD0, TT, (long)DD0 * TT, (long)TT * DD0);

  proj_kernel<<<dim3(TT / 128, BSZ), blk, 0, stream>>>(W1, Xt, Dbuf0);

  dim3 sblk(512);
  dim3 sgrid(TT / 256, NROW / 256);
  stage_kernel<1><<<sgrid, sblk, 0, stream>>>(Dbuf0, Wt[0], Mbuf, Dbuf1);
  stage_kernel<0><<<sgrid, sblk, 0, stream>>>(Dbuf1, Wt[1], Mbuf, Dbuf0);
  stage_kernel<0><<<sgrid, sblk, 0, stream>>>(Dbuf0, Wt[2], Mbuf, Dbuf1);
  stage_kernel<0><<<sgrid, sblk, 0, stream>>>(Dbuf1, Wt[3], Mbuf, Dbuf0);

  out_proj<<<dim3(NROW), blk, 0, stream>>>(Dbuf0, W2, Bb, Y);
}